// Round 1
// baseline (223.758 us; speedup 1.0000x reference)
//
#include <hip/hip_runtime.h>
#include <math.h>

#define MU_MAXC 32
#define MV_MAXC 32
#define OUT_UC  64
#define OUT_VC  64
#define DEG     3
#define NKNOT   (MU_MAXC + DEG + 1)   // 36
#define EPSV    1e-5f

// ws layout: acc[0]=ctrl diff2 sum, acc[1]=mask sum, acc[2]=surf sq-err sum; then int bad
__global__ void zero_ws_kernel(double* acc, int* bad) {
    acc[0] = 0.0; acc[1] = 0.0; acc[2] = 0.0; bad[0] = 0;
}

__launch_bounds__(256)
__global__ void nurbs_loss_kernel(const float* __restrict__ ctrl_pred,
                                  const float* __restrict__ ctrl_gt,
                                  const float* __restrict__ mask,
                                  const float* __restrict__ xyz,
                                  double* __restrict__ acc,
                                  int* __restrict__ badflag)
{
    const int b   = blockIdx.x;
    const int tid = threadIdx.x;

    __shared__ float s_ctrl[MU_MAXC * MV_MAXC * 3];   // 12 KB, [i][j][d]
    __shared__ float s_Bu[OUT_UC * 33];               // padded stride 33
    __shared__ float s_Bv[OUT_VC * 33];
    __shared__ float s_tmp[OUT_UC * MV_MAXC * 3];     // 24 KB, [u][j][d]
    __shared__ float s_sumBu[OUT_UC];
    __shared__ float s_sumBv[OUT_VC];
    __shared__ float s_knots_u[NKNOT];
    __shared__ float s_knots_v[NKNOT];
    __shared__ int   s_rowany[MU_MAXC];
    __shared__ int   s_colany[MV_MAXC];
    __shared__ int   s_mu, s_mv;
    __shared__ float s_red[256];

    if (tid < 32) { s_rowany[tid] = 0; s_colany[tid] = 0; }
    __syncthreads();

    // ---- Phase A: ctrl loss partials, mask row/col flags, stage ctrl to LDS ----
    float lsum_mask = 0.f, lsum_diff = 0.f;
    for (int k = 0; k < 4; k++) {
        const int cell = tid + 256 * k;               // 0..1023  = i*32+j
        const int base = (b * 1024 + cell) * 3;
        const float m  = mask[b * 1024 + cell];
        const float p0 = ctrl_pred[base + 0], p1 = ctrl_pred[base + 1], p2 = ctrl_pred[base + 2];
        const float g0 = ctrl_gt[base + 0],   g1 = ctrl_gt[base + 1],   g2 = ctrl_gt[base + 2];
        s_ctrl[cell * 3 + 0] = p0; s_ctrl[cell * 3 + 1] = p1; s_ctrl[cell * 3 + 2] = p2;
        const float d0 = p0 - g0, d1 = p1 - g1, d2 = p2 - g2;
        lsum_mask += m;
        lsum_diff += m * (d0 * d0 + d1 * d1 + d2 * d2);
        if (m > 0.f) { s_rowany[cell >> 5] = 1; s_colany[cell & 31] = 1; }
    }
    __syncthreads();

    if (tid == 0) {
        int cu = 0, cv = 0;
        #pragma unroll
        for (int i = 0; i < 32; i++) { cu += s_rowany[i]; cv += s_colany[i]; }
        s_mu = cu > (DEG + 1) ? cu : (DEG + 1);
        s_mv = cv > (DEG + 1) ? cv : (DEG + 1);
    }

    // ---- reduce mask sum ----
    s_red[tid] = lsum_mask; __syncthreads();
    for (int off = 128; off > 0; off >>= 1) {
        if (tid < off) s_red[tid] += s_red[tid + off];
        __syncthreads();
    }
    if (tid == 0) atomicAdd(&acc[1], (double)s_red[0]);
    __syncthreads();
    // ---- reduce ctrl diff2 sum ----
    s_red[tid] = lsum_diff; __syncthreads();
    for (int off = 128; off > 0; off >>= 1) {
        if (tid < off) s_red[tid] += s_red[tid + off];
        __syncthreads();
    }
    if (tid == 0) atomicAdd(&acc[0], (double)s_red[0]);
    __syncthreads();

    // ---- Phase B: knot vectors (open uniform, clamped, padded entries -> 1.0) ----
    if (tid < NKNOT) {
        const int L = s_mu + DEG + 1;
        s_knots_u[tid] = (tid <= DEG) ? 0.f
                        : ((tid >= L - 1 - DEG) ? 1.f : (float)tid / (float)(L - 1));
    } else if (tid >= 64 && tid < 64 + NKNOT) {
        const int k = tid - 64;
        const int L = s_mv + DEG + 1;
        s_knots_v[k] = (k <= DEG) ? 0.f
                      : ((k >= L - 1 - DEG) ? 1.f : (float)k / (float)(L - 1));
    }
    __syncthreads();

    // ---- Phase C: Cox-de Boor basis. threads 0..63 -> Bu rows, 64..127 -> Bv rows ----
    if (tid < 128) {
        const bool isU = tid < 64;
        const int t = isU ? tid : (tid - 64);
        const float* kv = isU ? s_knots_u : s_knots_v;
        const float step = (1.f - 2.f * EPSV) / 63.f;
        const float uu = (t == 63) ? (1.f - EPSV) : (EPSV + step * (float)t);

        float N[NKNOT - 1];   // 35
        #pragma unroll
        for (int k = 0; k < NKNOT - 1; k++)
            N[k] = (uu >= kv[k] && uu < kv[k + 1]) ? 1.f : 0.f;
        #pragma unroll
        for (int d = 1; d <= DEG; d++) {
            #pragma unroll
            for (int k = 0; k < NKNOT - 1 - d; k++) {
                const float den1 = kv[k + d] - kv[k];
                const float den2 = kv[k + d + 1] - kv[k + 1];
                const float s1 = (den1 > 0.f) ? (uu - kv[k]) / den1 : 0.f;
                const float s2 = (den2 > 0.f) ? (kv[k + d + 1] - uu) / den2 : 0.f;
                N[k] = s1 * N[k] + s2 * N[k + 1];   // in-place fwd: reads old N[k], N[k+1]
            }
        }
        float s = 0.f;
        float* Bdst = isU ? s_Bu : s_Bv;
        #pragma unroll
        for (int i = 0; i < 32; i++) { Bdst[t * 33 + i] = N[i]; s += N[i]; }
        if (isU) s_sumBu[t] = s; else s_sumBv[t] = s;
    }
    __syncthreads();

    // ---- Phase C2: tmp[u][j][d] = sum_i Bu[u][i] * ctrl[i][j][d] ----
    for (int k = 0; k < 24; k++) {
        const int flat = tid + 256 * k;               // < 6144
        const int u = flat / 96;
        const int r = flat - u * 96;                  // j*3 + d
        const float* Bu = &s_Bu[u * 33];
        const float* cp = &s_ctrl[r];
        float a = 0.f;
        #pragma unroll
        for (int i = 0; i < 32; i++) a += Bu[i] * cp[i * 96];
        s_tmp[flat] = a;
    }
    __syncthreads();

    // ---- Phase D: surf eval + squared error vs xyz ----
    float lsum_surf = 0.f;
    int bad = 0;
    for (int k = 0; k < 16; k++) {
        const int p = tid + 256 * k;                  // 0..4095, wave covers one u, all v
        const int u = p >> 6, v = p & 63;
        const float* Bv = &s_Bv[v * 33];
        const float* tp = &s_tmp[u * 96];
        float n0 = 0.f, n1 = 0.f, n2 = 0.f;
        #pragma unroll
        for (int j = 0; j < 32; j++) {
            const float w = Bv[j];
            n0 += w * tp[j * 3 + 0];
            n1 += w * tp[j * 3 + 1];
            n2 += w * tp[j * 3 + 2];
        }
        const float den = s_sumBu[u] * s_sumBv[v];
        const float x0 = n0 / den, x1 = n1 / den, x2 = n2 / den;
        const int base = (b * 4096 + p) * 3;
        const float d0 = x0 - xyz[base + 0];
        const float d1 = x1 - xyz[base + 1];
        const float d2 = x2 - xyz[base + 2];
        lsum_surf += d0 * d0 + d1 * d1 + d2 * d2;
        if (!isfinite(x0) || !isfinite(x1) || !isfinite(x2)) bad = 1;
    }
    s_red[tid] = lsum_surf; __syncthreads();
    for (int off = 128; off > 0; off >>= 1) {
        if (tid < off) s_red[tid] += s_red[tid + off];
        __syncthreads();
    }
    if (tid == 0) atomicAdd(&acc[2], (double)s_red[0]);
    if (bad) atomicOr(badflag, 1);
}

__global__ void finalize_kernel(const double* __restrict__ acc,
                                const int* __restrict__ bad,
                                float* __restrict__ out, int Bcnt)
{
    const double denom_c = acc[1] * 3.0;
    const double lc = acc[0] / (denom_c > 1.0 ? denom_c : 1.0);
    const double ls = acc[2] / ((double)Bcnt * OUT_UC * OUT_VC * 3.0);
    out[0] = (float)(lc + ls);           // total (computed before nan-guard, per ref)
    out[1] = (float)lc;                  // loss_ctrl
    out[2] = bad[0] ? 1.0e6f : (float)ls; // surf_mse with nan/inf guard
}

extern "C" void kernel_launch(void* const* d_in, const int* in_sizes, int n_in,
                              void* d_out, int out_size, void* d_ws, size_t ws_size,
                              hipStream_t stream)
{
    const float* pred = (const float*)d_in[0];
    const float* gt   = (const float*)d_in[1];
    const float* mask = (const float*)d_in[2];
    const float* xyz  = (const float*)d_in[3];
    const int Bcnt = in_sizes[2] / (MU_MAXC * MV_MAXC);   // 1024

    double* acc = (double*)d_ws;
    int* bad = (int*)(acc + 3);
    float* out = (float*)d_out;

    hipLaunchKernelGGL(zero_ws_kernel, dim3(1), dim3(1), 0, stream, acc, bad);
    hipLaunchKernelGGL(nurbs_loss_kernel, dim3(Bcnt), dim3(256), 0, stream,
                       pred, gt, mask, xyz, acc, bad);
    hipLaunchKernelGGL(finalize_kernel, dim3(1), dim3(1), 0, stream, acc, bad, out, Bcnt);
}

// Round 2
// 115.178 us; speedup vs baseline: 1.9427x; 1.9427x over previous
//
#include <hip/hip_runtime.h>
#include <math.h>

#define MU_MAXC 32
#define MV_MAXC 32
#define OUT_UC  64
#define OUT_VC  64
#define DEG     3
#define NKNOT   (MU_MAXC + DEG + 1)   // 36
#define EPSV    1e-5f

// ---------------- atomic-fallback helpers (used only if ws too small) ----
__global__ void zero_ws_kernel(double* acc, int* bad) {
    acc[0] = 0.0; acc[1] = 0.0; acc[2] = 0.0; bad[0] = 0;
}

// MODE 0: per-block partials  pd[b], pd[B+b], pd[2B+b], badp[b]
// MODE 1: atomicAdd into pd[0..2], atomicOr badp[0]
template <int MODE>
__launch_bounds__(256, 5)
__global__ void nurbs_loss_kernel(const float* __restrict__ ctrl_pred,
                                  const float* __restrict__ ctrl_gt,
                                  const float* __restrict__ mask,
                                  const float* __restrict__ xyz,
                                  double* __restrict__ pd, int Bcnt,
                                  int* __restrict__ badp)
{
    const int b   = blockIdx.x;
    const int tid = threadIdx.x;

    __shared__ float s_tmp[OUT_UC * MV_MAXC * 3];    // 24 KB  [u][j][d]
    __shared__ float s_Bu4[4 * OUT_UC];              // SoA [r][u]
    __shared__ float s_Bv4[4 * OUT_VC];              // SoA [r][v]
    __shared__ int   s_uoff[OUT_UC];
    __shared__ int   s_voff[OUT_VC];
    __shared__ float s_sumBu[OUT_UC];
    __shared__ float s_sumBv[OUT_VC];
    __shared__ float s_knots_u[NKNOT];
    __shared__ float s_knots_v[NKNOT];
    __shared__ int   s_rowany[MU_MAXC];
    __shared__ int   s_colany[MV_MAXC];
    __shared__ int   s_mu, s_mv, s_bad;
    __shared__ float s_wred[4], s_wred2[4];
    __shared__ float s_ctrl_diff, s_ctrl_mask;

    if (tid < 32) { s_rowany[tid] = 0; s_colany[tid] = 0; }
    if (tid == 0) s_bad = 0;
    __syncthreads();

    // ---- Phase A: masked ctrl MSE partials + mask row/col-any flags ----
    float lsum_mask = 0.f, lsum_diff = 0.f;
    for (int k = 0; k < 4; k++) {
        const int cell = tid + 256 * k;               // i*32+j
        const int base = (b * 1024 + cell) * 3;
        const float m  = mask[b * 1024 + cell];
        const float p0 = ctrl_pred[base + 0], p1 = ctrl_pred[base + 1], p2 = ctrl_pred[base + 2];
        const float g0 = ctrl_gt[base + 0],   g1 = ctrl_gt[base + 1],   g2 = ctrl_gt[base + 2];
        const float d0 = p0 - g0, d1 = p1 - g1, d2 = p2 - g2;
        lsum_mask += m;
        lsum_diff += m * (d0 * d0 + d1 * d1 + d2 * d2);
        if (m > 0.f) { s_rowany[cell >> 5] = 1; s_colany[cell & 31] = 1; }
    }
    // wave-level reduce (no LDS, no sync)
    #pragma unroll
    for (int off = 32; off > 0; off >>= 1) {
        lsum_mask += __shfl_down(lsum_mask, off);
        lsum_diff += __shfl_down(lsum_diff, off);
    }
    if ((tid & 63) == 0) { s_wred[tid >> 6] = lsum_mask; s_wred2[tid >> 6] = lsum_diff; }
    __syncthreads();

    if (tid == 0) {
        int cu = 0, cv = 0;
        #pragma unroll
        for (int i = 0; i < 32; i++) { cu += s_rowany[i]; cv += s_colany[i]; }
        s_mu = cu > (DEG + 1) ? cu : (DEG + 1);
        s_mv = cv > (DEG + 1) ? cv : (DEG + 1);
        s_ctrl_mask = s_wred[0] + s_wred[1] + s_wred[2] + s_wred[3];
        s_ctrl_diff = s_wred2[0] + s_wred2[1] + s_wred2[2] + s_wred2[3];
    }
    __syncthreads();

    // ---- Phase B: clamped open-uniform knots (padded entries -> 1.0) ----
    if (tid < NKNOT) {
        const int L = s_mu + DEG + 1;
        s_knots_u[tid] = (tid <= DEG) ? 0.f
                        : ((tid >= L - 1 - DEG) ? 1.f : (float)tid / (float)(L - 1));
    } else if (tid >= 64 && tid < 64 + NKNOT) {
        const int k = tid - 64;
        const int L = s_mv + DEG + 1;
        s_knots_v[k] = (k <= DEG) ? 0.f
                      : ((k >= L - 1 - DEG) ? 1.f : (float)k / (float)(L - 1));
    }
    __syncthreads();

    // ---- Phase C: span-based Cox-de Boor (only 4 nonzero weights) ----
    if (tid < 128) {
        const bool isU = tid < 64;
        const int t = isU ? tid : (tid - 64);
        const float* kv = isU ? s_knots_u : s_knots_v;
        const float step = (1.f - 2.f * EPSV) / 63.f;
        const float uu = (t == 63) ? (1.f - EPSV) : (EPSV + step * (float)t);

        // span = largest k with kv[k] <= uu  (then kv[span+1] > uu)
        int span = DEG;
        #pragma unroll
        for (int k = DEG + 1; k < NKNOT - 1; k++)
            if (kv[k] <= uu) span = k;

        // NURBS Book A2.2: N4[r] = basis[span-DEG+r]
        float N4[DEG + 1], left[DEG + 1], right[DEG + 1];
        N4[0] = 1.f;
        #pragma unroll
        for (int j = 1; j <= DEG; j++) {
            left[j]  = uu - kv[span + 1 - j];
            right[j] = kv[span + j] - uu;
            float saved = 0.f;
            #pragma unroll
            for (int r = 0; r < j; r++) {
                const float temp = N4[r] / (right[r + 1] + left[j - r]);
                N4[r] = saved + right[r + 1] * temp;
                saved = left[j - r] * temp;
            }
            N4[j] = saved;
        }
        const float s = N4[0] + N4[1] + N4[2] + N4[3];
        const int off = span - DEG;                    // in [0, 28]
        if (isU) {
            #pragma unroll
            for (int r = 0; r < 4; r++) s_Bu4[r * 64 + t] = N4[r];
            s_uoff[t] = off; s_sumBu[t] = s;
        } else {
            #pragma unroll
            for (int r = 0; r < 4; r++) s_Bv4[r * 64 + t] = N4[r];
            s_voff[t] = off; s_sumBv[t] = s;
        }
    }
    __syncthreads();

    // ---- Phase C2: tmp[u][j][d] = sum_{r<4} Bu4[u][r] * ctrl[uoff+r][j][d]
    const float* ctrlb = ctrl_pred + (size_t)b * 1024 * 3;
    for (int k = 0; k < 24; k++) {
        const int flat = tid + 256 * k;               // u*96 + (j*3+d), < 6144
        const int u = flat / 96;
        const int jd = flat - u * 96;
        const int off = s_uoff[u];
        float a = 0.f;
        #pragma unroll
        for (int r = 0; r < 4; r++)
            a += s_Bu4[r * 64 + u] * ctrlb[(off + r) * 96 + jd];
        s_tmp[flat] = a;
    }
    __syncthreads();

    // ---- Phase D: surf eval (4-wide over v) + squared error vs xyz ----
    float lsum_surf = 0.f;
    int bad = 0;
    for (int k = 0; k < 16; k++) {
        const int p = tid + 256 * k;                  // wave-uniform u, v=lane
        const int u = p >> 6, v = p & 63;
        const float* tp = &s_tmp[u * 96 + s_voff[v] * 3];
        float n0 = 0.f, n1 = 0.f, n2 = 0.f;
        #pragma unroll
        for (int r = 0; r < 4; r++) {
            const float w = s_Bv4[r * 64 + v];
            n0 += w * tp[r * 3 + 0];
            n1 += w * tp[r * 3 + 1];
            n2 += w * tp[r * 3 + 2];
        }
        const float inv = 1.0f / (s_sumBu[u] * s_sumBv[v]);
        const float x0 = n0 * inv, x1 = n1 * inv, x2 = n2 * inv;
        const int base = (b * 4096 + p) * 3;
        const float d0 = x0 - xyz[base + 0];
        const float d1 = x1 - xyz[base + 1];
        const float d2 = x2 - xyz[base + 2];
        lsum_surf += d0 * d0 + d1 * d1 + d2 * d2;
        if (!isfinite(x0) || !isfinite(x1) || !isfinite(x2)) bad = 1;
    }
    #pragma unroll
    for (int off = 32; off > 0; off >>= 1)
        lsum_surf += __shfl_down(lsum_surf, off);
    if ((tid & 63) == 0) s_wred[tid >> 6] = lsum_surf;
    if (bad) atomicOr(&s_bad, 1);
    __syncthreads();

    if (tid == 0) {
        const double surf = (double)s_wred[0] + s_wred[1] + s_wred[2] + s_wred[3];
        if (MODE == 0) {
            pd[b]             = (double)s_ctrl_diff;
            pd[Bcnt + b]      = (double)s_ctrl_mask;
            pd[2 * Bcnt + b]  = surf;
            badp[b]           = s_bad;
        } else {
            atomicAdd(&pd[0], (double)s_ctrl_diff);
            atomicAdd(&pd[1], (double)s_ctrl_mask);
            atomicAdd(&pd[2], surf);
            if (s_bad) atomicOr(badp, 1);
        }
    }
}

__global__ void finalize_partials_kernel(const double* __restrict__ pd,
                                         const int* __restrict__ badp,
                                         float* __restrict__ out, int Bcnt)
{
    __shared__ double sd0[4], sd1[4], sd2[4];
    __shared__ int sb[4];
    const int tid = threadIdx.x;
    double a0 = 0.0, a1 = 0.0, a2 = 0.0; int bad = 0;
    for (int i = tid; i < Bcnt; i += 256) {
        a0 += pd[i]; a1 += pd[Bcnt + i]; a2 += pd[2 * Bcnt + i];
        bad |= badp[i];
    }
    #pragma unroll
    for (int off = 32; off > 0; off >>= 1) {
        a0 += __shfl_down(a0, off);
        a1 += __shfl_down(a1, off);
        a2 += __shfl_down(a2, off);
        bad |= __shfl_down(bad, off);
    }
    if ((tid & 63) == 0) { const int w = tid >> 6; sd0[w] = a0; sd1[w] = a1; sd2[w] = a2; sb[w] = bad; }
    __syncthreads();
    if (tid == 0) {
        double d0 = 0, d1 = 0, d2 = 0; int bb = 0;
        #pragma unroll
        for (int i = 0; i < 4; i++) { d0 += sd0[i]; d1 += sd1[i]; d2 += sd2[i]; bb |= sb[i]; }
        const double denc = d1 * 3.0;
        const double lc = d0 / (denc > 1.0 ? denc : 1.0);
        const double ls = d2 / ((double)Bcnt * OUT_UC * OUT_VC * 3.0);
        out[0] = (float)(lc + ls);
        out[1] = (float)lc;
        out[2] = bb ? 1.0e6f : (float)ls;
    }
}

__global__ void finalize_atomic_kernel(const double* __restrict__ acc,
                                       const int* __restrict__ bad,
                                       float* __restrict__ out, int Bcnt)
{
    const double denc = acc[1] * 3.0;
    const double lc = acc[0] / (denc > 1.0 ? denc : 1.0);
    const double ls = acc[2] / ((double)Bcnt * OUT_UC * OUT_VC * 3.0);
    out[0] = (float)(lc + ls);
    out[1] = (float)lc;
    out[2] = bad[0] ? 1.0e6f : (float)ls;
}

extern "C" void kernel_launch(void* const* d_in, const int* in_sizes, int n_in,
                              void* d_out, int out_size, void* d_ws, size_t ws_size,
                              hipStream_t stream)
{
    const float* pred = (const float*)d_in[0];
    const float* gt   = (const float*)d_in[1];
    const float* mask = (const float*)d_in[2];
    const float* xyz  = (const float*)d_in[3];
    const int Bcnt = in_sizes[2] / (MU_MAXC * MV_MAXC);   // 1024

    double* pd = (double*)d_ws;
    float* out = (float*)d_out;

    const size_t need = (size_t)3 * Bcnt * sizeof(double) + (size_t)Bcnt * sizeof(int);
    if (ws_size >= need) {
        int* badp = (int*)(pd + 3 * Bcnt);
        hipLaunchKernelGGL((nurbs_loss_kernel<0>), dim3(Bcnt), dim3(256), 0, stream,
                           pred, gt, mask, xyz, pd, Bcnt, badp);
        hipLaunchKernelGGL(finalize_partials_kernel, dim3(1), dim3(256), 0, stream,
                           pd, badp, out, Bcnt);
    } else {
        int* badp = (int*)(pd + 3);
        hipLaunchKernelGGL(zero_ws_kernel, dim3(1), dim3(1), 0, stream, pd, badp);
        hipLaunchKernelGGL((nurbs_loss_kernel<1>), dim3(Bcnt), dim3(256), 0, stream,
                           pred, gt, mask, xyz, pd, Bcnt, badp);
        hipLaunchKernelGGL(finalize_atomic_kernel, dim3(1), dim3(1), 0, stream,
                           pd, badp, out, Bcnt);
    }
}